// Round 22
// baseline (111.796 us; speedup 1.0000x reference)
//
#include <hip/hip_runtime.h>
#include <hip/hip_bf16.h>

// B=8, T=1024, D=512, H=8, DH=64, VS=512
typedef __bf16 bf16;
typedef __bf16 bf16x8 __attribute__((ext_vector_type(8)));
typedef __bf16 bf16x4 __attribute__((ext_vector_type(4)));
typedef float f32x4 __attribute__((ext_vector_type(4)));
typedef int   i32x4 __attribute__((ext_vector_type(4)));

__device__ inline f32x4 mfma16(bf16x8 a, bf16x8 b, f32x4 c) {
    return __builtin_amdgcn_mfma_f32_16x16x32_bf16(a, b, c, 0, 0, 0);
}
__device__ inline bf16x8 ld8(const bf16* p) { return *reinterpret_cast<const bf16x8*>(p); }
__device__ inline f32x4 ldf4(const float* p) { return *reinterpret_cast<const f32x4*>(p); }

// ---------------- fused tables: pe2 (swizzled) + wcvt x3 + kcvt ----------------
// blocks [0,256): pe2; [256,448): wcvt; [448,4544): kcvt
__global__ __launch_bounds__(256) void tables_kernel(const float* __restrict__ W0, const float* __restrict__ W1,
                                                     const float* __restrict__ W2, const float* __restrict__ kin,
                                                     bf16* __restrict__ pe2, bf16* __restrict__ T0,
                                                     bf16* __restrict__ T1, bf16* __restrict__ T2,
                                                     bf16* __restrict__ kw) {
    __shared__ float tile[64][65];
    int bid = blockIdx.x;
    if (bid < 256) {
        int g = bid * 256 + threadIdx.x;       // 65536 = 1024 j x 64 d
        int j = g >> 6, d = g & 63;
        float w = __expf(-(float)(d & 31) * 0.29710775393471563f);   // ln(10000)/31
        float ang = (float)j * w;
        float v = (d < 32) ? sinf(ang) : cosf(ang);
        int idx = (((j >> 4) << 1) + (d >> 5)) * 512 + (((d >> 3) & 3) * 16 + (j & 15)) * 8 + (d & 7);
        pe2[idx] = (bf16)v;
    } else if (bid < 448) {
        int wb = bid - 256;
        int which = wb >> 6, bidx = wb & 63;
        const float* W = which == 0 ? W0 : which == 1 ? W1 : W2;
        bf16* Wt = which == 0 ? T0 : which == 1 ? T1 : T2;
        int tx = bidx & 7, ty = bidx >> 3;
        int lane = threadIdx.x & 63, w = threadIdx.x >> 6;
        #pragma unroll
        for (int i = 0; i < 16; i++) {
            int k = ty * 64 + w * 16 + i;
            tile[w * 16 + i][lane] = W[k * 512 + tx * 64 + lane];
        }
        __syncthreads();
        #pragma unroll
        for (int i = 0; i < 16; i++) {
            int n = tx * 64 + w * 16 + i;
            Wt[n * 512 + ty * 64 + lane] = (bf16)tile[lane][w * 16 + i];
        }
    } else {
        int i = ((bid - 448) * 256 + threadIdx.x) * 4;
        f32x4 v = ldf4(kin + i);
        int dh = i & 63, hh = (i >> 6) & 7, t = (i >> 9) & 1023, b = i >> 19;
        int bh = (b << 3) + hh;
        bf16x4 o;
        #pragma unroll
        for (int e = 0; e < 4; e++) o[e] = (bf16)v[e];
        int blk = ((bh << 6) + (t >> 4)) * 2 + (dh >> 5);
        int off = (((dh >> 3) & 3) * 16 + (t & 15)) * 8 + (dh & 7);
        *reinterpret_cast<bf16x4*>(kw + blk * 512 + off) = o;
    }
}

// ---------------- merged q+v proj: 64x64/BK32, pre-transposed bf16 W ----------------
// blockIdx.z==0: query -> q_ws (linear [bh][t][dh]); z==1: value -> v_ws (fragment-swizzled V^T)
__global__ __launch_bounds__(256) void proj_qv(const float* __restrict__ Q, const float* __restrict__ V,
                                               const bf16* __restrict__ WtQ, const bf16* __restrict__ WtV,
                                               const float* __restrict__ bq, const float* __restrict__ bv,
                                               bf16* __restrict__ q_ws, bf16* __restrict__ v_ws) {
    __shared__ bf16 As[64][40];
    __shared__ bf16 Bs[64][40];
    int isv = blockIdx.z;
    const float* A = isv ? V : Q;
    const bf16* Wt = isv ? WtV : WtQ;
    const float* bias = isv ? bv : bq;
    int row0 = blockIdx.x * 64, n0 = blockIdx.y * 64;
    int tid = threadIdx.x, lane = tid & 63, w = tid >> 6, lg = lane >> 4, lr = lane & 15;
    int wm = (w >> 1) * 32, wn = (w & 1) * 32;
    f32x4 acc[2][2] = {};
    for (int k0 = 0; k0 < 512; k0 += 32) {
        int r = tid >> 2, kq = (tid & 3) * 8;
        f32x4 a0 = ldf4(A + (row0 + r) * 512 + k0 + kq);
        f32x4 a1 = ldf4(A + (row0 + r) * 512 + k0 + kq + 4);
        bf16x8 av;
        #pragma unroll
        for (int e = 0; e < 4; e++) { av[e] = (bf16)a0[e]; av[4 + e] = (bf16)a1[e]; }
        bf16x8 bv8 = ld8(Wt + (n0 + r) * 512 + k0 + kq);
        __syncthreads();
        *reinterpret_cast<bf16x8*>(&As[r][kq]) = av;
        *reinterpret_cast<bf16x8*>(&Bs[r][kq]) = bv8;
        __syncthreads();
        bf16x8 aa0 = ld8(&As[wm + lr][lg * 8]);
        bf16x8 aa1 = ld8(&As[wm + 16 + lr][lg * 8]);
        bf16x8 bb0 = ld8(&Bs[wn + lr][lg * 8]);
        bf16x8 bb1 = ld8(&Bs[wn + 16 + lr][lg * 8]);
        acc[0][0] = mfma16(aa0, bb0, acc[0][0]);
        acc[0][1] = mfma16(aa0, bb1, acc[0][1]);
        acc[1][0] = mfma16(aa1, bb0, acc[1][0]);
        acc[1][1] = mfma16(aa1, bb1, acc[1][1]);
    }
    #pragma unroll
    for (int mi = 0; mi < 2; mi++)
    #pragma unroll
    for (int ni = 0; ni < 2; ni++) {
        int rowb = row0 + wm + mi * 16 + lg * 4;
        int col = n0 + wn + ni * 16 + lr;
        int b = rowb >> 10, t = rowb & 1023, hh = col >> 6, dh = col & 63;
        int bh = (b << 3) + hh;
        if (isv) {
            int blk = (((bh << 4) + (t >> 6)) * 2 + ((t >> 5) & 1)) * 4 + (dh >> 4);
            int off = (((t >> 3) & 3) * 16 + (dh & 15)) * 8 + (t & 7);
            bf16x4 o4;
            #pragma unroll
            for (int rr = 0; rr < 4; rr++) o4[rr] = (bf16)((float)acc[mi][ni][rr] + bias[col]);
            *reinterpret_cast<bf16x4*>(v_ws + blk * 512 + off) = o4;
        } else {
            #pragma unroll
            for (int rr = 0; rr < 4; rr++) {
                float v = (float)acc[mi][ni][rr] + bias[col];
                q_ws[((bh << 10) + t + rr) * 64 + dh] = (bf16)v;
            }
        }
    }
}

// ---------------- output proj: 64x64/BK32, bf16 A (x_ws), fp32 out ----------------
__global__ __launch_bounds__(256) void proj_o(const bf16* __restrict__ Ap, const bf16* __restrict__ Wt,
                                              const float* __restrict__ bias, float* __restrict__ outp) {
    __shared__ bf16 As[64][40];
    __shared__ bf16 Bs[64][40];
    int row0 = blockIdx.x * 64, n0 = blockIdx.y * 64;
    int tid = threadIdx.x, lane = tid & 63, w = tid >> 6, lg = lane >> 4, lr = lane & 15;
    int wm = (w >> 1) * 32, wn = (w & 1) * 32;
    f32x4 acc[2][2] = {};
    for (int k0 = 0; k0 < 512; k0 += 32) {
        int r = tid >> 2, kq = (tid & 3) * 8;
        bf16x8 av = ld8(Ap + (row0 + r) * 512 + k0 + kq);
        bf16x8 bv = ld8(Wt + (n0 + r) * 512 + k0 + kq);
        __syncthreads();
        *reinterpret_cast<bf16x8*>(&As[r][kq]) = av;
        *reinterpret_cast<bf16x8*>(&Bs[r][kq]) = bv;
        __syncthreads();
        bf16x8 a0 = ld8(&As[wm + lr][lg * 8]);
        bf16x8 a1 = ld8(&As[wm + 16 + lr][lg * 8]);
        bf16x8 b0 = ld8(&Bs[wn + lr][lg * 8]);
        bf16x8 b1 = ld8(&Bs[wn + 16 + lr][lg * 8]);
        acc[0][0] = mfma16(a0, b0, acc[0][0]);
        acc[0][1] = mfma16(a0, b1, acc[0][1]);
        acc[1][0] = mfma16(a1, b0, acc[1][0]);
        acc[1][1] = mfma16(a1, b1, acc[1][1]);
    }
    #pragma unroll
    for (int mi = 0; mi < 2; mi++)
    #pragma unroll
    for (int ni = 0; ni < 2; ni++) {
        int rowb = row0 + wm + mi * 16 + lg * 4;
        int col = n0 + wn + ni * 16 + lr;
        #pragma unroll
        for (int rr = 0; rr < 4; rr++)
            outp[(rowb + rr) * 512 + col] = (float)acc[mi][ni][rr] + bias[col];
    }
}

// ---------------- fused TENER attention: swapped-QK, vector P stores, pipelined ----------------
// grid (64 bh, 32 qt-pairs), block 256 = 4 waves. Logit S[i][j] = q_i.k_j + q2_i.pe2[j].
// SWAPPED QK^T: S^T = mfma(K,Q) -> lane (lg,lr) holds P[i=lr][j=16nt+4lg+r], so the
// Pl store is 4 vector b64 writes/tile (was 16 scalar b16) — DS ops 18->6/tile.
// PV side unchanged (b128 row reads). Pipeline + double-buffered Pl (r21).
// Fixed-zero-max softmax (r19); d = P.1 on matrix pipe (r20). No branches (r15),
// KVBLK=64 (r17), (256,4) no-tighter (r5/r10/r12).
__global__ __launch_bounds__(256, 4) void tener_attn(const bf16* __restrict__ qw, const bf16* __restrict__ kw,
                                                     const bf16* __restrict__ vt, const int* __restrict__ mask,
                                                     const bf16* __restrict__ pe2, const float* __restrict__ v_bias,
                                                     bf16* __restrict__ xw) {
    __shared__ bf16 Pl[2][4][16][76];  // double-buffered per-wave P [row i][col j]
    __shared__ float Oo[2][16][65];    // odd-wave partial O per pair; col 64 = denominator
    int bh = blockIdx.x, b = bh >> 3, h = bh & 7;
    int tid = threadIdx.x, w = tid >> 6, lane = tid & 63, lg = lane >> 4, lr = lane & 15;
    int rbase = (blockIdx.y * 2 + (w >> 1)) * 16;
    int jh = w & 1;

    const int* mkb = mask + (b << 10);

    int qoff = ((bh << 10) + rbase + lr) * 64 + lg * 8;
    bf16x8 aq0 = ld8(qw + qoff);
    bf16x8 aq1 = ld8(qw + qoff + 32);

    // build q2 fragments in-register: q2 = R(-t)(q + v_bias[h]).
    bf16x8 aq2, aq3;
    {
        int t = rbase + lr;
        const float* vbp = v_bias + (h << 6) + lg * 8;
        #pragma unroll
        for (int e = 0; e < 8; e++) {
            int d = lg * 8 + e;
            float as = (float)aq0[e] + vbp[e];
            float ac = (float)aq1[e] + vbp[32 + e];
            float w_ = __expf(-(float)d * 0.29710775393471563f);
            float sa, ca;
            __sincosf((float)t * w_, &sa, &ca);
            aq2[e] = (bf16)(as * ca + ac * sa);
            aq3[e] = (bf16)(ac * ca - as * sa);
        }
    }

    // constant ones-fragment: B operand for the denominator MFMA (d = P . 1)
    bf16x8 ones;
    #pragma unroll
    for (int e = 0; e < 8; e++) ones[e] = (bf16)1.0f;

    f32x4 o[4] = {};
    f32x4 od = {};                     // od[r] = denominator of row 4*lg+r

    // SWAPPED: S^T = K.Q -> s[nt][r] = S[j0+16nt+4lg+r][rbase+lr]
    auto computeS = [&](f32x4* sarr, int j0) {
        int kblk = (bh << 6) + (j0 >> 4);
        int pblk = j0 >> 4;
        #pragma unroll
        for (int nt = 0; nt < 4; nt++) {
            const bf16* kp = kw + (((kblk + nt) << 1)) * 512 + lane * 8;
            const bf16* pp = pe2 + (((pblk + nt) << 1)) * 512 + lane * 8;
            f32x4 acc = {};
            acc = mfma16(ld8(kp), aq0, acc);
            acc = mfma16(ld8(kp + 512), aq1, acc);
            acc = mfma16(ld8(pp), aq2, acc);
            acc = mfma16(ld8(pp + 512), aq3, acc);
            sarr[nt] = acc;
        }
    };
    // store P[i=lr][j=16nt+4lg+r] as one bf16x4 vector write per nt
    auto expStore = [&](f32x4* sarr, int j0, int cur) {
        #pragma unroll
        for (int nt = 0; nt < 4; nt++) {
            i32x4 mk4 = *reinterpret_cast<const i32x4*>(mkb + j0 + nt * 16 + lg * 4);
            bf16x4 o4;
            #pragma unroll
            for (int r = 0; r < 4; r++) {
                float p = mk4[r] ? __expf((float)sarr[nt][r]) : 0.f;
                o4[r] = (bf16)p;
            }
            *reinterpret_cast<bf16x4*>(&Pl[cur][w][lr][nt * 16 + lg * 4]) = o4;
        }
    };
    auto pv = [&](int j0, int cur) {
        int vblk0 = ((((bh << 4) + (j0 >> 6)) << 1)) << 2;
        #pragma unroll
        for (int ks = 0; ks < 2; ks++) {
            bf16x8 ap = ld8(&Pl[cur][w][lr][ks * 32 + lg * 8]);
            od = mfma16(ap, ones, od);
            #pragma unroll
            for (int dt = 0; dt < 4; dt++) {
                const bf16* vp = vt + (vblk0 + (ks << 2) + dt) * 512 + lane * 8;
                o[dt] = mfma16(ap, ld8(vp), o[dt]);
            }
        }
    };

    f32x4 s[4];
    computeS(s, jh * 512);
    #pragma unroll
    for (int tt = 0; tt < 7; tt++) {
        int j0 = jh * 512 + tt * 64;
        int cur = tt & 1;
        expStore(s, j0, cur);
        computeS(s, j0 + 64);          // next tile's S: overlaps exp + PV below
        __builtin_amdgcn_sched_barrier(0x7F);   // DS may not cross (Pl write->read fence)
        pv(j0, cur);
    }
    expStore(s, jh * 512 + 448, 1);
    __builtin_amdgcn_sched_barrier(0x7F);
    pv(jh * 512 + 448, 1);

    // pair-merge: partials sum directly (shared implicit max of 0)
    if (w & 1) {
        #pragma unroll
        for (int dt = 0; dt < 4; dt++)
        #pragma unroll
        for (int r = 0; r < 4; r++)
            Oo[w >> 1][4 * lg + r][dt * 16 + lr] = o[dt][r];
        if (lr == 0) {
            #pragma unroll
            for (int r = 0; r < 4; r++) Oo[w >> 1][4 * lg + r][64] = od[r];
        }
    }
    __syncthreads();
    if (!(w & 1)) {
        #pragma unroll
        for (int r = 0; r < 4; r++) {
            int rl = 4 * lg + r;
            float dd = od[r] + Oo[w >> 1][rl][64];
            float inv = dd > 0.f ? 1.f / dd : 0.f;
            int row = rbase + rl;
            #pragma unroll
            for (int dt = 0; dt < 4; dt++) {
                float v = (o[dt][r] + Oo[w >> 1][rl][dt * 16 + lr]) * inv;
                xw[(((b << 10) + row) << 9) + (h << 6) + dt * 16 + lr] = (bf16)v;
            }
        }
    }
}

extern "C" void kernel_launch(void* const* d_in, const int* in_sizes, int n_in,
                              void* d_out, int out_size, void* d_ws, size_t ws_size,
                              hipStream_t stream) {
    const float* query  = (const float*)d_in[0];
    const float* key_in = (const float*)d_in[1];
    const float* value  = (const float*)d_in[2];
    const int*   mask   = (const int*)d_in[3];
    const float* Wq     = (const float*)d_in[4];
    const float* bq     = (const float*)d_in[5];
    const float* Wv     = (const float*)d_in[6];
    const float* bv     = (const float*)d_in[7];
    const float* Wo     = (const float*)d_in[8];
    const float* bo     = (const float*)d_in[9];
    const float* v_bias = (const float*)d_in[10];

    char* ws = (char*)d_ws;
    bf16*  pe2  = (bf16*)(ws);                           // 128 KB (swizzled, pos=j)
    bf16*  q_ws = (bf16*)(ws + 327680);                  // 8 MB  [bh][t][dh]
    bf16*  v_ws = (bf16*)(ws + 327680 + 8388608);        // 8 MB  V^T fragment-swizzled
    bf16*  x_ws = (bf16*)(ws + 327680 + 16777216);       // 8 MB  [b*t][512]
    bf16*  wt_q = (bf16*)(ws + 327680 + 25165824);       // 512 KB  Wq^T bf16
    bf16*  wt_v = (bf16*)(ws + 327680 + 25690112);       // 512 KB  Wv^T bf16
    bf16*  wt_o = (bf16*)(ws + 327680 + 26214400);       // 512 KB  Wo^T bf16
    // k_ws lives in d_out's first 8 MB; fully consumed by tener_attn before
    // proj_o overwrites d_out.
    bf16*  k_ws = (bf16*)d_out;

    tables_kernel<<<4544, 256, 0, stream>>>(Wq, Wv, Wo, key_in, pe2, wt_q, wt_v, wt_o, k_ws);
    proj_qv<<<dim3(128, 8, 2), 256, 0, stream>>>(query, value, wt_q, wt_v, bq, bv, q_ws, v_ws);
    tener_attn<<<dim3(64, 32), 256, 0, stream>>>(q_ws, k_ws, v_ws, mask, pe2, v_bias, x_ws);
    proj_o<<<dim3(128, 8), 256, 0, stream>>>(x_ws, wt_o, bo, (float*)d_out);
}

// Round 23
// 104.457 us; speedup vs baseline: 1.0703x; 1.0703x over previous
//
#include <hip/hip_runtime.h>
#include <hip/hip_bf16.h>

// B=8, T=1024, D=512, H=8, DH=64, VS=512
typedef __bf16 bf16;
typedef __bf16 bf16x8 __attribute__((ext_vector_type(8)));
typedef __bf16 bf16x4 __attribute__((ext_vector_type(4)));
typedef float f32x4 __attribute__((ext_vector_type(4)));

__device__ inline f32x4 mfma16(bf16x8 a, bf16x8 b, f32x4 c) {
    return __builtin_amdgcn_mfma_f32_16x16x32_bf16(a, b, c, 0, 0, 0);
}
__device__ inline bf16x8 ld8(const bf16* p) { return *reinterpret_cast<const bf16x8*>(p); }
__device__ inline f32x4 ldf4(const float* p) { return *reinterpret_cast<const f32x4*>(p); }

// ---------------- fused tables: pe2 (swizzled) + wcvt x3 + kcvt ----------------
// blocks [0,256): pe2; [256,448): wcvt; [448,4544): kcvt
__global__ __launch_bounds__(256) void tables_kernel(const float* __restrict__ W0, const float* __restrict__ W1,
                                                     const float* __restrict__ W2, const float* __restrict__ kin,
                                                     bf16* __restrict__ pe2, bf16* __restrict__ T0,
                                                     bf16* __restrict__ T1, bf16* __restrict__ T2,
                                                     bf16* __restrict__ kw) {
    __shared__ float tile[64][65];
    int bid = blockIdx.x;
    if (bid < 256) {
        int g = bid * 256 + threadIdx.x;       // 65536 = 1024 j x 64 d
        int j = g >> 6, d = g & 63;
        float w = __expf(-(float)(d & 31) * 0.29710775393471563f);   // ln(10000)/31
        float ang = (float)j * w;
        float v = (d < 32) ? sinf(ang) : cosf(ang);
        int idx = (((j >> 4) << 1) + (d >> 5)) * 512 + (((d >> 3) & 3) * 16 + (j & 15)) * 8 + (d & 7);
        pe2[idx] = (bf16)v;
    } else if (bid < 448) {
        int wb = bid - 256;
        int which = wb >> 6, bidx = wb & 63;
        const float* W = which == 0 ? W0 : which == 1 ? W1 : W2;
        bf16* Wt = which == 0 ? T0 : which == 1 ? T1 : T2;
        int tx = bidx & 7, ty = bidx >> 3;
        int lane = threadIdx.x & 63, w = threadIdx.x >> 6;
        #pragma unroll
        for (int i = 0; i < 16; i++) {
            int k = ty * 64 + w * 16 + i;
            tile[w * 16 + i][lane] = W[k * 512 + tx * 64 + lane];
        }
        __syncthreads();
        #pragma unroll
        for (int i = 0; i < 16; i++) {
            int n = tx * 64 + w * 16 + i;
            Wt[n * 512 + ty * 64 + lane] = (bf16)tile[lane][w * 16 + i];
        }
    } else {
        int i = ((bid - 448) * 256 + threadIdx.x) * 4;
        f32x4 v = ldf4(kin + i);
        int dh = i & 63, hh = (i >> 6) & 7, t = (i >> 9) & 1023, b = i >> 19;
        int bh = (b << 3) + hh;
        bf16x4 o;
        #pragma unroll
        for (int e = 0; e < 4; e++) o[e] = (bf16)v[e];
        int blk = ((bh << 6) + (t >> 4)) * 2 + (dh >> 5);
        int off = (((dh >> 3) & 3) * 16 + (t & 15)) * 8 + (dh & 7);
        *reinterpret_cast<bf16x4*>(kw + blk * 512 + off) = o;
    }
}

// ---------------- merged q+v proj: 64x64/BK32, pre-transposed bf16 W ----------------
// blockIdx.z==0: query -> q_ws (linear [bh][t][dh]); z==1: value -> v_ws (fragment-swizzled V^T)
__global__ __launch_bounds__(256) void proj_qv(const float* __restrict__ Q, const float* __restrict__ V,
                                               const bf16* __restrict__ WtQ, const bf16* __restrict__ WtV,
                                               const float* __restrict__ bq, const float* __restrict__ bv,
                                               bf16* __restrict__ q_ws, bf16* __restrict__ v_ws) {
    __shared__ bf16 As[64][40];
    __shared__ bf16 Bs[64][40];
    int isv = blockIdx.z;
    const float* A = isv ? V : Q;
    const bf16* Wt = isv ? WtV : WtQ;
    const float* bias = isv ? bv : bq;
    int row0 = blockIdx.x * 64, n0 = blockIdx.y * 64;
    int tid = threadIdx.x, lane = tid & 63, w = tid >> 6, lg = lane >> 4, lr = lane & 15;
    int wm = (w >> 1) * 32, wn = (w & 1) * 32;
    f32x4 acc[2][2] = {};
    for (int k0 = 0; k0 < 512; k0 += 32) {
        int r = tid >> 2, kq = (tid & 3) * 8;
        f32x4 a0 = ldf4(A + (row0 + r) * 512 + k0 + kq);
        f32x4 a1 = ldf4(A + (row0 + r) * 512 + k0 + kq + 4);
        bf16x8 av;
        #pragma unroll
        for (int e = 0; e < 4; e++) { av[e] = (bf16)a0[e]; av[4 + e] = (bf16)a1[e]; }
        bf16x8 bv8 = ld8(Wt + (n0 + r) * 512 + k0 + kq);
        __syncthreads();
        *reinterpret_cast<bf16x8*>(&As[r][kq]) = av;
        *reinterpret_cast<bf16x8*>(&Bs[r][kq]) = bv8;
        __syncthreads();
        bf16x8 aa0 = ld8(&As[wm + lr][lg * 8]);
        bf16x8 aa1 = ld8(&As[wm + 16 + lr][lg * 8]);
        bf16x8 bb0 = ld8(&Bs[wn + lr][lg * 8]);
        bf16x8 bb1 = ld8(&Bs[wn + 16 + lr][lg * 8]);
        acc[0][0] = mfma16(aa0, bb0, acc[0][0]);
        acc[0][1] = mfma16(aa0, bb1, acc[0][1]);
        acc[1][0] = mfma16(aa1, bb0, acc[1][0]);
        acc[1][1] = mfma16(aa1, bb1, acc[1][1]);
    }
    #pragma unroll
    for (int mi = 0; mi < 2; mi++)
    #pragma unroll
    for (int ni = 0; ni < 2; ni++) {
        int rowb = row0 + wm + mi * 16 + lg * 4;
        int col = n0 + wn + ni * 16 + lr;
        int b = rowb >> 10, t = rowb & 1023, hh = col >> 6, dh = col & 63;
        int bh = (b << 3) + hh;
        if (isv) {
            int blk = (((bh << 4) + (t >> 6)) * 2 + ((t >> 5) & 1)) * 4 + (dh >> 4);
            int off = (((t >> 3) & 3) * 16 + (dh & 15)) * 8 + (t & 7);
            bf16x4 o4;
            #pragma unroll
            for (int rr = 0; rr < 4; rr++) o4[rr] = (bf16)((float)acc[mi][ni][rr] + bias[col]);
            *reinterpret_cast<bf16x4*>(v_ws + blk * 512 + off) = o4;
        } else {
            #pragma unroll
            for (int rr = 0; rr < 4; rr++) {
                float v = (float)acc[mi][ni][rr] + bias[col];
                q_ws[((bh << 10) + t + rr) * 64 + dh] = (bf16)v;
            }
        }
    }
}

// ---------------- output proj: 64x64/BK32, bf16 A (x_ws), fp32 out ----------------
__global__ __launch_bounds__(256) void proj_o(const bf16* __restrict__ Ap, const bf16* __restrict__ Wt,
                                              const float* __restrict__ bias, float* __restrict__ outp) {
    __shared__ bf16 As[64][40];
    __shared__ bf16 Bs[64][40];
    int row0 = blockIdx.x * 64, n0 = blockIdx.y * 64;
    int tid = threadIdx.x, lane = tid & 63, w = tid >> 6, lg = lane >> 4, lr = lane & 15;
    int wm = (w >> 1) * 32, wn = (w & 1) * 32;
    f32x4 acc[2][2] = {};
    for (int k0 = 0; k0 < 512; k0 += 32) {
        int r = tid >> 2, kq = (tid & 3) * 8;
        bf16x8 av = ld8(Ap + (row0 + r) * 512 + k0 + kq);
        bf16x8 bv = ld8(Wt + (n0 + r) * 512 + k0 + kq);
        __syncthreads();
        *reinterpret_cast<bf16x8*>(&As[r][kq]) = av;
        *reinterpret_cast<bf16x8*>(&Bs[r][kq]) = bv;
        __syncthreads();
        bf16x8 a0 = ld8(&As[wm + lr][lg * 8]);
        bf16x8 a1 = ld8(&As[wm + 16 + lr][lg * 8]);
        bf16x8 b0 = ld8(&Bs[wn + lr][lg * 8]);
        bf16x8 b1 = ld8(&Bs[wn + 16 + lr][lg * 8]);
        acc[0][0] = mfma16(a0, b0, acc[0][0]);
        acc[0][1] = mfma16(a0, b1, acc[0][1]);
        acc[1][0] = mfma16(a1, b0, acc[1][0]);
        acc[1][1] = mfma16(a1, b1, acc[1][1]);
    }
    #pragma unroll
    for (int mi = 0; mi < 2; mi++)
    #pragma unroll
    for (int ni = 0; ni < 2; ni++) {
        int rowb = row0 + wm + mi * 16 + lg * 4;
        int col = n0 + wn + ni * 16 + lr;
        #pragma unroll
        for (int rr = 0; rr < 4; rr++)
            outp[(rowb + rr) * 512 + col] = (float)acc[mi][ni][rr] + bias[col];
    }
}

// ---------------- fused TENER attention: software-pipelined S/exp/PV, double-buffered Pl ----------------
// grid (64 bh, 32 qt-pairs), block 256 = 4 waves. Logit S[i][j] = q_i.k_j + q2_i.pe2[j],
// q2 built in-register (RoPE fold of rel+vb).
// Pipeline: exp(t)->Pl[cur] ; S(t+1) MFMAs issued between exp(t) and PV(t).
// Fixed-zero-max softmax (r19); d = P.1 on the matrix pipe (r20).
// MEASURED-BEST CONFIG (r21 = 63.4us attn / 104.7 total). Rejected mutations:
// occupancy up (r5/r10 spill), K-reg prefetch (r12 spill), defer-branch (r15 +4us),
// KVBLK=128 (r17 +23us), operand-swapped QK + vector P stores (r22 +6us).
__global__ __launch_bounds__(256, 4) void tener_attn(const bf16* __restrict__ qw, const bf16* __restrict__ kw,
                                                     const bf16* __restrict__ vt, const int* __restrict__ mask,
                                                     const bf16* __restrict__ pe2, const float* __restrict__ v_bias,
                                                     bf16* __restrict__ xw) {
    __shared__ bf16 Pl[2][4][16][76];  // double-buffered per-wave P relayout
    __shared__ float Oo[2][16][65];    // odd-wave partial O per pair; col 64 = denominator
    int bh = blockIdx.x, b = bh >> 3, h = bh & 7;
    int tid = threadIdx.x, w = tid >> 6, lane = tid & 63, lg = lane >> 4, lr = lane & 15;
    int rbase = (blockIdx.y * 2 + (w >> 1)) * 16;
    int jh = w & 1;

    const int* mkb = mask + (b << 10);

    int qoff = ((bh << 10) + rbase + lr) * 64 + lg * 8;
    bf16x8 aq0 = ld8(qw + qoff);
    bf16x8 aq1 = ld8(qw + qoff + 32);

    // build q2 fragments in-register: q2 = R(-t)(q + v_bias[h]).
    bf16x8 aq2, aq3;
    {
        int t = rbase + lr;
        const float* vbp = v_bias + (h << 6) + lg * 8;
        #pragma unroll
        for (int e = 0; e < 8; e++) {
            int d = lg * 8 + e;
            float as = (float)aq0[e] + vbp[e];
            float ac = (float)aq1[e] + vbp[32 + e];
            float w_ = __expf(-(float)d * 0.29710775393471563f);
            float sa, ca;
            __sincosf((float)t * w_, &sa, &ca);
            aq2[e] = (bf16)(as * ca + ac * sa);
            aq3[e] = (bf16)(ac * ca - as * sa);
        }
    }

    // constant ones-fragment: B operand for the denominator MFMA (d = P . 1)
    bf16x8 ones;
    #pragma unroll
    for (int e = 0; e < 8; e++) ones[e] = (bf16)1.0f;

    f32x4 o[4] = {};
    f32x4 od = {};                     // od[r] = denominator of row 4*lg+r

    auto computeS = [&](f32x4* sarr, int j0) {
        int kblk = (bh << 6) + (j0 >> 4);
        int pblk = j0 >> 4;
        #pragma unroll
        for (int nt = 0; nt < 4; nt++) {
            const bf16* kp = kw + (((kblk + nt) << 1)) * 512 + lane * 8;
            const bf16* pp = pe2 + (((pblk + nt) << 1)) * 512 + lane * 8;
            f32x4 acc = {};
            acc = mfma16(aq0, ld8(kp), acc);
            acc = mfma16(aq1, ld8(kp + 512), acc);
            acc = mfma16(aq2, ld8(pp), acc);
            acc = mfma16(aq3, ld8(pp + 512), acc);
            sarr[nt] = acc;
        }
    };
    auto expStore = [&](f32x4* sarr, int j0, int cur) {
        int mk[4];
        #pragma unroll
        for (int nt = 0; nt < 4; nt++) mk[nt] = mkb[j0 + nt * 16 + lr];
        #pragma unroll
        for (int r = 0; r < 4; r++) {
            int rl = 4 * lg + r;
            #pragma unroll
            for (int nt = 0; nt < 4; nt++) {
                float p = mk[nt] ? __expf((float)sarr[nt][r]) : 0.f;
                Pl[cur][w][rl][nt * 16 + lr] = (bf16)p;
            }
        }
    };
    auto pv = [&](int j0, int cur) {
        int vblk0 = ((((bh << 4) + (j0 >> 6)) << 1)) << 2;
        #pragma unroll
        for (int ks = 0; ks < 2; ks++) {
            bf16x8 ap = ld8(&Pl[cur][w][lr][ks * 32 + lg * 8]);
            od = mfma16(ap, ones, od);
            #pragma unroll
            for (int dt = 0; dt < 4; dt++) {
                const bf16* vp = vt + (vblk0 + (ks << 2) + dt) * 512 + lane * 8;
                o[dt] = mfma16(ap, ld8(vp), o[dt]);
            }
        }
    };

    f32x4 s[4];
    computeS(s, jh * 512);
    #pragma unroll
    for (int tt = 0; tt < 7; tt++) {
        int j0 = jh * 512 + tt * 64;
        int cur = tt & 1;
        expStore(s, j0, cur);
        computeS(s, j0 + 64);          // next tile's S: overlaps exp + PV below
        __builtin_amdgcn_sched_barrier(0x7F);   // DS may not cross (Pl write->read fence)
        pv(j0, cur);
    }
    expStore(s, jh * 512 + 448, 1);
    __builtin_amdgcn_sched_barrier(0x7F);
    pv(jh * 512 + 448, 1);

    // pair-merge: partials sum directly (shared implicit max of 0)
    if (w & 1) {
        #pragma unroll
        for (int dt = 0; dt < 4; dt++)
        #pragma unroll
        for (int r = 0; r < 4; r++)
            Oo[w >> 1][4 * lg + r][dt * 16 + lr] = o[dt][r];
        if (lr == 0) {
            #pragma unroll
            for (int r = 0; r < 4; r++) Oo[w >> 1][4 * lg + r][64] = od[r];
        }
    }
    __syncthreads();
    if (!(w & 1)) {
        #pragma unroll
        for (int r = 0; r < 4; r++) {
            int rl = 4 * lg + r;
            float dd = od[r] + Oo[w >> 1][rl][64];
            float inv = dd > 0.f ? 1.f / dd : 0.f;
            int row = rbase + rl;
            #pragma unroll
            for (int dt = 0; dt < 4; dt++) {
                float v = (o[dt][r] + Oo[w >> 1][rl][dt * 16 + lr]) * inv;
                xw[(((b << 10) + row) << 9) + (h << 6) + dt * 16 + lr] = (bf16)v;
            }
        }
    }
}

extern "C" void kernel_launch(void* const* d_in, const int* in_sizes, int n_in,
                              void* d_out, int out_size, void* d_ws, size_t ws_size,
                              hipStream_t stream) {
    const float* query  = (const float*)d_in[0];
    const float* key_in = (const float*)d_in[1];
    const float* value  = (const float*)d_in[2];
    const int*   mask   = (const int*)d_in[3];
    const float* Wq     = (const float*)d_in[4];
    const float* bq     = (const float*)d_in[5];
    const float* Wv     = (const float*)d_in[6];
    const float* bv     = (const float*)d_in[7];
    const float* Wo     = (const float*)d_in[8];
    const float* bo     = (const float*)d_in[9];
    const float* v_bias = (const float*)d_in[10];

    char* ws = (char*)d_ws;
    bf16*  pe2  = (bf16*)(ws);                           // 128 KB (swizzled, pos=j)
    bf16*  q_ws = (bf16*)(ws + 327680);                  // 8 MB  [bh][t][dh]
    bf16*  v_ws = (bf16*)(ws + 327680 + 8388608);        // 8 MB  V^T fragment-swizzled
    bf16*  x_ws = (bf16*)(ws + 327680 + 16777216);       // 8 MB  [b*t][512]
    bf16*  wt_q = (bf16*)(ws + 327680 + 25165824);       // 512 KB  Wq^T bf16
    bf16*  wt_v = (bf16*)(ws + 327680 + 25690112);       // 512 KB  Wv^T bf16
    bf16*  wt_o = (bf16*)(ws + 327680 + 26214400);       // 512 KB  Wo^T bf16
    // k_ws lives in d_out's first 8 MB; fully consumed by tener_attn before
    // proj_o overwrites d_out.
    bf16*  k_ws = (bf16*)d_out;

    tables_kernel<<<4544, 256, 0, stream>>>(Wq, Wv, Wo, key_in, pe2, wt_q, wt_v, wt_o, k_ws);
    proj_qv<<<dim3(128, 8, 2), 256, 0, stream>>>(query, value, wt_q, wt_v, bq, bv, q_ws, v_ws);
    tener_attn<<<dim3(64, 32), 256, 0, stream>>>(q_ws, k_ws, v_ws, mask, pe2, v_bias, x_ws);
    proj_o<<<dim3(128, 8), 256, 0, stream>>>(x_ws, wt_o, bo, (float*)d_out);
}